// Round 3
// baseline (719.612 us; speedup 1.0000x reference)
//
#include <hip/hip_runtime.h>
#include <stdint.h>
#include <stddef.h>

// ---------------------------------------------------------------------------
// Gemma2AttentionWithExpert: fused two-stream QKV(+RoPE) + GQA attention +
// per-stream output projection.  All GEMMs via f16 MFMA (16x16x32), fp32 acc.
// B=4, L1=1024, L2=512, L=1536, D_PG=2304, D_EX=1024, H=8, HKV=4, DH=256.
// Round 3: RoPE fused into QKV epilogue via head-dim pair interleave (QK^T is
// invariant under a consistent head-dim permutation), f16 mask, tail merge
// (pv_b3 + oproj b0-2 in one launch).
// ---------------------------------------------------------------------------

typedef _Float16 f16;
typedef _Float16 f16x8 __attribute__((ext_vector_type(8)));
typedef _Float16 f16x4 __attribute__((ext_vector_type(4)));
typedef float    f32x4 __attribute__((ext_vector_type(4)));

__device__ __forceinline__ void async_ld16(const void* g, void* l) {
  __builtin_amdgcn_global_load_lds((const __attribute__((address_space(1))) void*)g,
                                   (__attribute__((address_space(3))) void*)l,
                                   16, 0, 0);
}

// ---- 128x128 tile GEMM core, A:[M,K] row-major (lda), B:[N,K] row-major
// (ldb) i.e. B^T layout, K % 32 == 0.  256 threads = 4 waves as 2x2 of 64x64.
template <typename Epi>
__device__ __forceinline__ void gemm_core(f16* At, f16* Bt,
                                          const f16* __restrict__ A, int lda,
                                          const f16* __restrict__ Bm, int ldb,
                                          int K, Epi&& epi)
{
  const int t    = threadIdx.x;
  const int w    = t >> 6;
  const int lane = t & 63;
  const int q4   = lane >> 4;
  const int l16  = lane & 15;
  const int wm   = w >> 1;
  const int wn   = w & 1;

  const f32x4 vzero = {0.f, 0.f, 0.f, 0.f};
  f32x4 acc[4][4];
#pragma unroll
  for (int i = 0; i < 4; ++i)
#pragma unroll
    for (int j = 0; j < 4; ++j) acc[i][j] = vzero;

  const int srow = t >> 2;
  const int scol = (t & 3) << 3;
  const f16* aP = A  + (size_t)srow * lda + scol;
  const f16* bP = Bm + (size_t)srow * ldb + scol;
  f16* ldsA0 = At + w * 512;
  f16* ldsA1 = At + 2048 + w * 512;
  f16* ldsB0 = Bt + w * 512;
  f16* ldsB1 = Bt + 2048 + w * 512;
  const size_t a64 = (size_t)64 * lda;
  const size_t b64 = (size_t)64 * ldb;

  for (int k0 = 0; k0 < K; k0 += 32) {
    async_ld16(aP + k0,        ldsA0);
    async_ld16(aP + a64 + k0,  ldsA1);
    async_ld16(bP + k0,        ldsB0);
    async_ld16(bP + b64 + k0,  ldsB1);
    __syncthreads();

    f16x8 af[4], bf[4];
#pragma unroll
    for (int mi = 0; mi < 4; ++mi)
      af[mi] = *(const f16x8*)(At + (wm * 64 + mi * 16 + l16) * 32 + q4 * 8);
#pragma unroll
    for (int ni = 0; ni < 4; ++ni)
      bf[ni] = *(const f16x8*)(Bt + (wn * 64 + ni * 16 + l16) * 32 + q4 * 8);

#pragma unroll
    for (int mi = 0; mi < 4; ++mi)
#pragma unroll
      for (int ni = 0; ni < 4; ++ni)
        acc[mi][ni] = __builtin_amdgcn_mfma_f32_16x16x32_f16(af[mi], bf[ni], acc[mi][ni], 0, 0, 0);
    __syncthreads();
  }

  // C/D layout (m89-verified): row = quad*4 + reg, col = lane&15
#pragma unroll
  for (int mi = 0; mi < 4; ++mi)
#pragma unroll
    for (int ni = 0; ni < 4; ++ni)
#pragma unroll
      for (int r = 0; r < 4; ++r)
        epi(wm * 64 + mi * 16 + q4 * 4 + r, wn * 64 + ni * 16 + l16, acc[mi][ni][r]);
}

// ---- fused QKV + RoPE: both streams; q/k head-dims are PAIR-INTERLEAVED
// (weight rows were permuted in the cast), so the RoPE partner element is in
// the adjacent lane -> __shfl_xor(v,1).  q/k/v written f16, final.
// blocks [0,1024): stream0 (xpg @ W0cat, K=2304); [1024,1536): stream1.
__global__ __launch_bounds__(256) void k_qkv(
    const f16* __restrict__ xpg, const f16* __restrict__ xex,
    const f16* __restrict__ W0,  const f16* __restrict__ W1,
    const float* __restrict__ cs, const float* __restrict__ sn,
    f16* __restrict__ q, f16* __restrict__ k, f16* __restrict__ v)
{
  __shared__ alignas(16) f16 At[128 * 32];
  __shared__ alignas(16) f16 Bt[128 * 32];
  const int idx = blockIdx.x;
  const bool s0 = idx < 1024;
  int by, bx, K;
  const f16 *A, *B;
  if (s0) { by = idx >> 5; bx = idx & 31; K = 2304;
            A = xpg + (size_t)by * 128 * 2304; B = W0 + (size_t)bx * 128 * 2304; }
  else    { int j = idx - 1024; by = j >> 5; bx = j & 31; K = 1024;
            A = xex + (size_t)by * 128 * 1024; B = W1 + (size_t)bx * 128 * 1024; }
  const int rowbase = by * 128, colbase = bx * 128;
  gemm_core(At, Bt, A, K, B, K, K, [&](int r, int c, float fv) {
    int m = rowbase + r;
    int row = s0 ? ((m >> 10) * 1536 + (m & 1023))
                 : ((m >> 9) * 1536 + 1024 + (m & 511));
    int col = colbase + c;
    // partner for RoPE pair (adjacent lane holds col^1); uniform execution
    float p = __shfl_xor(fv, 1, 64);
    if (col < 3072) {
      int j = (col & 255) >> 1;
      float cv = cs[(size_t)row * 128 + j];
      float sv = sn[(size_t)row * 128 + j];
      float y = (col & 1) ? (fv * cv + p * sv) : (fv * cv - p * sv);
      f16 h = (f16)y;
      if (col < 2048) q[(size_t)row * 2048 + col]        = h;
      else            k[(size_t)row * 1024 + col - 2048] = h;
    } else {
      v[(size_t)row * 1024 + col - 3072] = (f16)fv;
    }
  });
}

// ---- V transpose: v[B*1536, 1024] -> vt[B][4][256][1536] -------------------
__global__ __launch_bounds__(256) void k_vtrans(const f16* __restrict__ v,
                                                f16* __restrict__ vt)
{
  __shared__ f16 tile[32][33];
  const int b = blockIdx.z;
  const int d0 = blockIdx.x * 32, l0 = blockIdx.y * 32;
  const int t = threadIdx.x;
  const int tr = t >> 5, tc = t & 31;
#pragma unroll
  for (int i = 0; i < 4; ++i) {
    int l = l0 + tr + i * 8;
    tile[tr + i * 8][tc] = v[((size_t)b * 1536 + l) * 1024 + d0 + tc];
  }
  __syncthreads();
#pragma unroll
  for (int i = 0; i < 4; ++i) {
    int d = d0 + tr + i * 8;
    int g = d >> 8, dw = d & 255;
    vt[(((size_t)b * 4 + g) * 256 + dw) * 1536 + l0 + tc] = tile[tc][tr + i * 8];
  }
}

// ---- attention mega-kernel: blocks [0,npv) do PV for batch b_pv reading
// Psrc; blocks [npv, npv+1152) do scores for batch b_sc writing f16 Sdst.
__global__ __launch_bounds__(256) void k_attn(
    const f16* __restrict__ qb, const f16* __restrict__ kb,
    const f16* __restrict__ mask, f16* __restrict__ Sdst,
    const f16* __restrict__ Psrc, const f16* __restrict__ vt,
    f16* __restrict__ att0, f16* __restrict__ att1,
    int b_sc, int b_pv, int npv)
{
  __shared__ alignas(16) f16 At[128 * 32];
  __shared__ alignas(16) f16 Bt[128 * 32];
  const int idx = blockIdx.x;
  if (idx < npv) {
    const int h = idx / 24, rem = idx % 24, by = rem >> 1, bx = rem & 1;
    const f16* A = Psrc + (size_t)h * 1536 * 1536 + (size_t)by * 128 * 1536;
    const f16* B = vt + (size_t)(b_pv * 4 + (h >> 1)) * 256 * 1536 + (size_t)bx * 128 * 1536;
    const int rowbase = by * 128, colbase = bx * 128;
    gemm_core(At, Bt, A, 1536, B, 1536, 1536, [&](int r, int c, float fv) {
      int m = rowbase + r;
      if (m < 1024) att0[((size_t)(b_pv * 1024 + m))       * 2048 + h * 256 + colbase + c] = (f16)fv;
      else          att1[((size_t)(b_pv * 512 + m - 1024)) * 2048 + h * 256 + colbase + c] = (f16)fv;
    });
  } else {
    const int j = idx - npv;
    const int h = j / 144, rem = j % 144, by = rem / 12, bx = rem % 12;
    const f16* A = qb + (size_t)b_sc * 1536 * 2048 + h * 256 + (size_t)by * 128 * 2048;
    const f16* B = kb + (size_t)b_sc * 1536 * 1024 + (h >> 1) * 256 + (size_t)bx * 128 * 1024;
    f16* Sz = Sdst + (size_t)h * 1536 * 1536;
    const f16* mb = mask + (size_t)b_sc * 1536 * 1536;
    const int rowbase = by * 128, colbase = bx * 128;
    gemm_core(At, Bt, A, 2048, B, 1024, 256, [&](int r, int c, float fv) {
      size_t i = (size_t)(rowbase + r) * 1536 + colbase + c;
      Sz[i] = (f16)(fv * 0.0625f + (float)mb[i]);
    });
  }
}

// ---- wave-per-row softmax over 1536, f16 in/out, in place ------------------
__global__ __launch_bounds__(256) void k_softmax(f16* __restrict__ S)
{
  const int row = blockIdx.x * 4 + (threadIdx.x >> 6);
  const int lane = threadIdx.x & 63;
  f16* p = S + (size_t)row * 1536 + lane * 8;
  f16x8 v0 = *(const f16x8*)p;
  f16x8 v1 = *(const f16x8*)(p + 512);
  f16x8 v2 = *(const f16x8*)(p + 1024);
  float x[24];
#pragma unroll
  for (int i = 0; i < 8; ++i) {
    x[i] = (float)v0[i]; x[8 + i] = (float)v1[i]; x[16 + i] = (float)v2[i];
  }
  float mx = x[0];
#pragma unroll
  for (int i = 1; i < 24; ++i) mx = fmaxf(mx, x[i]);
#pragma unroll
  for (int o = 32; o > 0; o >>= 1) mx = fmaxf(mx, __shfl_xor(mx, o, 64));
  float s = 0.f;
#pragma unroll
  for (int i = 0; i < 24; ++i) { x[i] = __expf(x[i] - mx); s += x[i]; }
#pragma unroll
  for (int o = 32; o > 0; o >>= 1) s += __shfl_xor(s, o, 64);
  const float inv = 1.f / s;
  f16x8 o0, o1, o2;
#pragma unroll
  for (int i = 0; i < 8; ++i) {
    o0[i] = (f16)(x[i] * inv); o1[i] = (f16)(x[8 + i] * inv); o2[i] = (f16)(x[16 + i] * inv);
  }
  *(f16x8*)p = o0; *(f16x8*)(p + 512) = o1; *(f16x8*)(p + 1024) = o2;
}

// ---- tail: [0,192) = PV for batch 3; [192,624) = oproj0 rows b0-2;
//      [624,720) = oproj1 rows b0-2 ----------------------------------------
__global__ __launch_bounds__(256) void k_tail(
    const f16* __restrict__ Psrc, const f16* __restrict__ vt,
    f16* __restrict__ att0, f16* __restrict__ att1,
    const f16* __restrict__ wo0, const f16* __restrict__ wo1,
    float* __restrict__ out0, float* __restrict__ out1)
{
  __shared__ alignas(16) f16 At[128 * 32];
  __shared__ alignas(16) f16 Bt[128 * 32];
  const int idx = blockIdx.x;
  if (idx < 192) {
    const int h = idx / 24, rem = idx % 24, by = rem >> 1, bx = rem & 1;
    const f16* A = Psrc + (size_t)h * 1536 * 1536 + (size_t)by * 128 * 1536;
    const f16* B = vt + (size_t)(3 * 4 + (h >> 1)) * 256 * 1536 + (size_t)bx * 128 * 1536;
    const int rowbase = by * 128, colbase = bx * 128;
    gemm_core(At, Bt, A, 1536, B, 1536, 1536, [&](int r, int c, float fv) {
      int m = rowbase + r;
      if (m < 1024) att0[((size_t)(3 * 1024 + m))       * 2048 + h * 256 + colbase + c] = (f16)fv;
      else          att1[((size_t)(3 * 512 + m - 1024)) * 2048 + h * 256 + colbase + c] = (f16)fv;
    });
  } else if (idx < 624) {
    const int j = idx - 192;
    const int by = j / 18, bx = j % 18;
    const f16* A = att0 + (size_t)by * 128 * 2048;
    const f16* B = wo0 + (size_t)bx * 128 * 2048;
    const int rowbase = by * 128, colbase = bx * 128;
    gemm_core(At, Bt, A, 2048, B, 2048, 2048, [&](int r, int c, float fv) {
      out0[(size_t)(rowbase + r) * 2304 + colbase + c] = fv;
    });
  } else {
    const int j = idx - 624;
    const int by = j >> 3, bx = j & 7;
    const f16* A = att1 + (size_t)by * 128 * 2048;
    const f16* B = wo1 + (size_t)bx * 128 * 2048;
    const int rowbase = by * 128, colbase = bx * 128;
    gemm_core(At, Bt, A, 2048, B, 2048, 2048, [&](int r, int c, float fv) {
      out1[(size_t)(rowbase + r) * 1024 + colbase + c] = fv;
    });
  }
}

// ---- oproj remainder: b3 rows.  [0,144): out0 by 24..31; [144,176): out1
// by 12..15 -----------------------------------------------------------------
__global__ __launch_bounds__(256) void k_oproj3(
    const f16* __restrict__ att0, const f16* __restrict__ att1,
    const f16* __restrict__ wo0,  const f16* __restrict__ wo1,
    float* __restrict__ out0, float* __restrict__ out1)
{
  __shared__ alignas(16) f16 At[128 * 32];
  __shared__ alignas(16) f16 Bt[128 * 32];
  const int idx = blockIdx.x;
  int by, bx, ldc;
  const f16 *A, *B;
  float* C;
  if (idx < 144) { by = 24 + idx / 18; bx = idx % 18;
                   A = att0 + (size_t)by * 128 * 2048; B = wo0 + (size_t)bx * 128 * 2048;
                   C = out0; ldc = 2304; }
  else           { int j = idx - 144; by = 12 + (j >> 3); bx = j & 7;
                   A = att1 + (size_t)by * 128 * 2048; B = wo1 + (size_t)bx * 128 * 2048;
                   C = out1; ldc = 1024; }
  const int rowbase = by * 128, colbase = bx * 128;
  gemm_core(At, Bt, A, 2048, B, 2048, 2048, [&](int r, int c, float fv) {
    C[(size_t)(rowbase + r) * ldc + colbase + c] = fv;
  });
}

// ---- flat cast fp32->f16 with per-source dst offsets (pg, ex, Wv0, Wo0,
// Wv1, Wo1) ------------------------------------------------------------------
__global__ __launch_bounds__(256) void k_cast_all(
    const float* __restrict__ s0, const float* __restrict__ s1,
    const float* __restrict__ s2, const float* __restrict__ s3,
    const float* __restrict__ s4, const float* __restrict__ s5,
    f16* __restrict__ ws)
{
  const size_t gid = ((size_t)blockIdx.x * 256 + threadIdx.x) * 4;
  const float* s; size_t off, dst;
  if      (gid < 9437184ull)  { s = s0; off = gid;               dst = 0ull        + off; }
  else if (gid < 11534336ull) { s = s1; off = gid - 9437184ull;  dst = 9437184ull  + off; }
  else if (gid < 13893632ull) { s = s2; off = gid - 11534336ull; dst = 18612224ull + off; }
  else if (gid < 18612224ull) { s = s3; off = gid - 13893632ull; dst = 20971520ull + off; }
  else if (gid < 19660800ull) { s = s4; off = gid - 18612224ull; dst = 28835840ull + off; }
  else                        { s = s5; off = gid - 19660800ull; dst = 29884416ull + off; }
  float4 v = *(const float4*)(s + off);
  f16x4 o = {(f16)v.x, (f16)v.y, (f16)v.z, (f16)v.w};
  *(f16x4*)(ws + dst) = o;
}

// ---- Wq/Wk cast with per-head RoPE pair interleave: dst row h*256+w reads
// src row h*256 + (w>>1) + 128*(w&1).  One block per dst row. ---------------
__global__ __launch_bounds__(256) void k_cast_wr(
    const float* __restrict__ wq0, const float* __restrict__ wk0,
    const float* __restrict__ wq1, const float* __restrict__ wk1,
    f16* __restrict__ W0c, f16* __restrict__ W1c)
{
  const int idx = blockIdx.x;
  const float* src; f16* dstm; int K, r, drow;
  if      (idx < 2048) { src = wq0; dstm = W0c; K = 2304; r = idx;        drow = idx; }
  else if (idx < 3072) { src = wk0; dstm = W0c; K = 2304; r = idx - 2048; drow = idx; }
  else if (idx < 5120) { src = wq1; dstm = W1c; K = 1024; r = idx - 3072; drow = idx - 3072; }
  else                 { src = wk1; dstm = W1c; K = 1024; r = idx - 5120; drow = idx - 3072; }
  const int w = r & 255;
  const int srow = (r & ~255) + (w >> 1) + ((w & 1) << 7);
  const float* sp = src + (size_t)srow * K;
  f16* dp = dstm + (size_t)drow * K;
  for (int c = threadIdx.x * 4; c < K; c += 1024) {
    float4 v = *(const float4*)(sp + c);
    f16x4 o = {(f16)v.x, (f16)v.y, (f16)v.z, (f16)v.w};
    *(f16x4*)(dp + c) = o;
  }
}

// ---- mask fp32 -> f16 ------------------------------------------------------
__global__ __launch_bounds__(256) void k_cast_mask(const float* __restrict__ m,
                                                   f16* __restrict__ mh)
{
  const size_t gid = ((size_t)blockIdx.x * 256 + threadIdx.x) * 4;
  float4 v = *(const float4*)(m + gid);
  f16x4 o = {(f16)v.x, (f16)v.y, (f16)v.z, (f16)v.w};
  *(f16x4*)(mh + gid) = o;
}

// ---------------------------------------------------------------------------
extern "C" void kernel_launch(void* const* d_in, const int* in_sizes, int n_in,
                              void* d_out, int out_size, void* d_ws, size_t ws_size,
                              hipStream_t stream)
{
  (void)in_sizes; (void)n_in; (void)out_size; (void)ws_size;
  const float* pg  = (const float*)d_in[0];
  const float* ex  = (const float*)d_in[1];
  const float* cs  = (const float*)d_in[2];
  const float* sn  = (const float*)d_in[3];
  const float* msk = (const float*)d_in[4];

  char* ws = (char*)d_ws;
  f16* xpg  = (f16*)(ws + 0);           // [4096,2304]   (dead after qkv)
  f16* xex  = (f16*)(ws + 18874368);    // [2048,1024]   (dead after qkv)
  f16* W0c  = (f16*)(ws + 23068672);    // [4096,2304] Wq0i;Wk0i;Wv0 (dead after qkv)
  f16* wo0c = (f16*)(ws + 41943040);    // [2304,2048]
  f16* W1c  = (f16*)(ws + 51380224);    // [4096,1024] Wq1i;Wk1i;Wv1 (dead after qkv)
  f16* wo1c = (f16*)(ws + 59768832);    // [1024,2048]
  f16* qb   = (f16*)(ws + 63963136);    // [B*1536, 2048] roped f16
  f16* kb   = (f16*)(ws + 89128960);    // [B*1536, 1024]
  f16* vb   = (f16*)(ws + 101711872);   // [B*1536, 1024] (dead after vtrans)
  f16* vt   = (f16*)(ws + 114294784);   // [B,4,256,1536]
  f16* att0 = (f16*)(ws + 126877696);   // [B*1024, 2048]
  f16* att1 = (f16*)(ws + 143654912);   // [B*512, 2048]
  f16* S0   = (f16*)(ws + 152043520);   // f16 S/P chunk A: 8*1536*1536
  f16* S1   = (f16*)(ws + 189792256);   // f16 S/P chunk B (ends 227,540,992)
  f16* mkh  = W0c;                      // f16 mask overlays dead W0c (18.9MB)
  float* out0 = (float*)d_out;          // [4,1024,2304]
  float* out1 = out0 + 9437184;         // [4,512,1024]

  // 1) casts: flat (pg, ex, Wv0, Wo0, Wv1, Wo1) + pair-interleaved Wq/Wk
  k_cast_all<<<21248, 256, 0, stream>>>(
      pg, ex, (const float*)d_in[7], (const float*)d_in[8],
      (const float*)d_in[11], (const float*)d_in[12], (f16*)ws);
  k_cast_wr<<<6144, 256, 0, stream>>>(
      (const float*)d_in[5], (const float*)d_in[6],
      (const float*)d_in[9], (const float*)d_in[10], W0c, W1c);

  // 2) fused QKV + RoPE (both streams, 1536 blocks)
  k_qkv<<<1536, 256, 0, stream>>>(xpg, xex, W0c, W1c, cs, sn, qb, kb, vb);

  // 3) mask -> f16 (into dead W0c region), V transpose
  k_cast_mask<<<9216, 256, 0, stream>>>(msk, mkh);
  k_vtrans<<<dim3(32, 48, 4), 256, 0, stream>>>(vb, vt);

  // 4) attention pipeline: pv_b fused into scores_{b+1} (double-buffered S)
  k_attn<<<1152, 256, 0, stream>>>(qb, kb, mkh, S0, S0, vt, att0, att1, 0, 0, 0);
  k_softmax<<<3072, 256, 0, stream>>>(S0);
  k_attn<<<1344, 256, 0, stream>>>(qb, kb, mkh, S1, S0, vt, att0, att1, 1, 0, 192);
  k_softmax<<<3072, 256, 0, stream>>>(S1);
  k_attn<<<1344, 256, 0, stream>>>(qb, kb, mkh, S0, S1, vt, att0, att1, 2, 1, 192);
  k_softmax<<<3072, 256, 0, stream>>>(S0);
  k_attn<<<1344, 256, 0, stream>>>(qb, kb, mkh, S1, S0, vt, att0, att1, 3, 2, 192);
  k_softmax<<<3072, 256, 0, stream>>>(S1);

  // 5) tail: pv_b3 + oproj rows b0-2 (720 blocks), then oproj b3 (176)
  k_tail<<<720, 256, 0, stream>>>(S1, vt, att0, att1, wo0c, wo1c, out0, out1);
  k_oproj3<<<176, 256, 0, stream>>>(att0, att1, wo0c, wo1c, out0, out1);
}

// Round 4
// 690.889 us; speedup vs baseline: 1.0416x; 1.0416x over previous
//
#include <hip/hip_runtime.h>
#include <stdint.h>
#include <stddef.h>

// ---------------------------------------------------------------------------
// Gemma2AttentionWithExpert: fused two-stream QKV + RoPE + GQA attention +
// per-stream output projection.  All GEMMs via f16 MFMA (16x16x32), fp32 acc.
// B=4, L1=1024, L2=512, L=1536, D_PG=2304, D_EX=1024, H=8, HKV=4, DH=256.
// Round 4: RoPE un-fused (round-3 fusion was a latency-bound gather epilogue,
// -31us) but weights stay pair-interleaved so the standalone rope pass is
// fully coalesced (f16x8 + float4 cos/sin).  rope+mask-cast+vtrans merged in
// one launch.  oproj(b) scheduled into the scores(b+2) mega-launch.
// ---------------------------------------------------------------------------

typedef _Float16 f16;
typedef _Float16 f16x8 __attribute__((ext_vector_type(8)));
typedef _Float16 f16x4 __attribute__((ext_vector_type(4)));
typedef float    f32x4 __attribute__((ext_vector_type(4)));

__device__ __forceinline__ void async_ld16(const void* g, void* l) {
  __builtin_amdgcn_global_load_lds((const __attribute__((address_space(1))) void*)g,
                                   (__attribute__((address_space(3))) void*)l,
                                   16, 0, 0);
}

// ---- 128x128 tile GEMM core, A:[M,K] row-major (lda), B:[N,K] row-major
// (ldb) i.e. B^T layout, K % 32 == 0.  256 threads = 4 waves as 2x2 of 64x64.
template <typename Epi>
__device__ __forceinline__ void gemm_core(f16* At, f16* Bt,
                                          const f16* __restrict__ A, int lda,
                                          const f16* __restrict__ Bm, int ldb,
                                          int K, Epi&& epi)
{
  const int t    = threadIdx.x;
  const int w    = t >> 6;
  const int lane = t & 63;
  const int q4   = lane >> 4;
  const int l16  = lane & 15;
  const int wm   = w >> 1;
  const int wn   = w & 1;

  const f32x4 vzero = {0.f, 0.f, 0.f, 0.f};
  f32x4 acc[4][4];
#pragma unroll
  for (int i = 0; i < 4; ++i)
#pragma unroll
    for (int j = 0; j < 4; ++j) acc[i][j] = vzero;

  const int srow = t >> 2;
  const int scol = (t & 3) << 3;
  const f16* aP = A  + (size_t)srow * lda + scol;
  const f16* bP = Bm + (size_t)srow * ldb + scol;
  f16* ldsA0 = At + w * 512;
  f16* ldsA1 = At + 2048 + w * 512;
  f16* ldsB0 = Bt + w * 512;
  f16* ldsB1 = Bt + 2048 + w * 512;
  const size_t a64 = (size_t)64 * lda;
  const size_t b64 = (size_t)64 * ldb;

  for (int k0 = 0; k0 < K; k0 += 32) {
    async_ld16(aP + k0,        ldsA0);
    async_ld16(aP + a64 + k0,  ldsA1);
    async_ld16(bP + k0,        ldsB0);
    async_ld16(bP + b64 + k0,  ldsB1);
    __syncthreads();

    f16x8 af[4], bf[4];
#pragma unroll
    for (int mi = 0; mi < 4; ++mi)
      af[mi] = *(const f16x8*)(At + (wm * 64 + mi * 16 + l16) * 32 + q4 * 8);
#pragma unroll
    for (int ni = 0; ni < 4; ++ni)
      bf[ni] = *(const f16x8*)(Bt + (wn * 64 + ni * 16 + l16) * 32 + q4 * 8);

#pragma unroll
    for (int mi = 0; mi < 4; ++mi)
#pragma unroll
      for (int ni = 0; ni < 4; ++ni)
        acc[mi][ni] = __builtin_amdgcn_mfma_f32_16x16x32_f16(af[mi], bf[ni], acc[mi][ni], 0, 0, 0);
    __syncthreads();
  }

  // C/D layout (m89-verified): row = quad*4 + reg, col = lane&15
#pragma unroll
  for (int mi = 0; mi < 4; ++mi)
#pragma unroll
    for (int ni = 0; ni < 4; ++ni)
#pragma unroll
      for (int r = 0; r < 4; ++r)
        epi(wm * 64 + mi * 16 + q4 * 4 + r, wn * 64 + ni * 16 + l16, acc[mi][ni][r]);
}

// ---- fused QKV: both streams, q/k/v written f16 (q/k pair-interleaved dims,
// roped afterwards in k_post).  blocks [0,1024): stream0; [1024,1536): s1.
__global__ __launch_bounds__(256) void k_qkv(
    const f16* __restrict__ xpg, const f16* __restrict__ xex,
    const f16* __restrict__ W0,  const f16* __restrict__ W1,
    f16* __restrict__ q, f16* __restrict__ k, f16* __restrict__ v)
{
  __shared__ alignas(16) f16 At[128 * 32];
  __shared__ alignas(16) f16 Bt[128 * 32];
  const int idx = blockIdx.x;
  const bool s0 = idx < 1024;
  int by, bx, K;
  const f16 *A, *B;
  if (s0) { by = idx >> 5; bx = idx & 31; K = 2304;
            A = xpg + (size_t)by * 128 * 2304; B = W0 + (size_t)bx * 128 * 2304; }
  else    { int j = idx - 1024; by = j >> 5; bx = j & 31; K = 1024;
            A = xex + (size_t)by * 128 * 1024; B = W1 + (size_t)bx * 128 * 1024; }
  const int rowbase = by * 128, colbase = bx * 128;
  gemm_core(At, Bt, A, K, B, K, K, [&](int r, int c, float fv) {
    int m = rowbase + r;
    int row = s0 ? ((m >> 10) * 1536 + (m & 1023))
                 : ((m >> 9) * 1536 + 1024 + (m & 511));
    int col = colbase + c;
    f16 h = (f16)fv;
    if      (col < 2048) q[(size_t)row * 2048 + col]        = h;
    else if (col < 3072) k[(size_t)row * 1024 + col - 2048] = h;
    else                 v[(size_t)row * 1024 + col - 3072] = h;
  });
}

// ---- post pass: [0,6144) vtrans; [6144,15360) mask->f16; [15360,24576)
// in-place RoPE on pair-interleaved q/k (f16x8 = 4 pairs, float4 cos/sin) ----
__global__ __launch_bounds__(256) void k_post(
    f16* __restrict__ q, f16* __restrict__ k,
    const float* __restrict__ cs, const float* __restrict__ sn,
    const float* __restrict__ msk, f16* __restrict__ mkh,
    const f16* __restrict__ v, f16* __restrict__ vt)
{
  const int blk = blockIdx.x;
  if (blk < 6144) {
    // V transpose: v[B*1536,1024] -> vt[B][4][256][1536]
    __shared__ f16 tile[32][33];
    const int b = blk / 1536, r0 = blk % 1536;
    const int d0 = (r0 & 31) * 32, l0 = (r0 >> 5) * 32;
    const int t = threadIdx.x;
    const int tr = t >> 5, tc = t & 31;
#pragma unroll
    for (int i = 0; i < 4; ++i)
      tile[tr + i * 8][tc] = v[((size_t)b * 1536 + l0 + tr + i * 8) * 1024 + d0 + tc];
    __syncthreads();
#pragma unroll
    for (int i = 0; i < 4; ++i) {
      int d = d0 + tr + i * 8;
      vt[(((size_t)b * 4 + (d >> 8)) * 256 + (d & 255)) * 1536 + l0 + tc] = tile[tc][tr + i * 8];
    }
  } else if (blk < 15360) {
    const size_t gid = ((size_t)(blk - 6144) * 256 + threadIdx.x) * 4;
    float4 m4 = *(const float4*)(msk + gid);
    f16x4 o = {(f16)m4.x, (f16)m4.y, (f16)m4.z, (f16)m4.w};
    *(f16x4*)(mkh + gid) = o;
  } else {
    const size_t tid8 = ((size_t)(blk - 15360) * 256 + threadIdx.x) * 8;
    f16* base; size_t row; int col;
    if (tid8 < 12582912ull) { base = q + tid8; row = tid8 >> 11; col = (int)(tid8 & 2047); }
    else { size_t f = tid8 - 12582912ull; base = k + f; row = f >> 10; col = (int)(f & 1023); }
    const int j0 = (col & 255) >> 1;
    f16x8 x = *(const f16x8*)base;
    float4 c4 = *(const float4*)(cs + row * 128 + j0);
    float4 s4 = *(const float4*)(sn + row * 128 + j0);
    f16x8 o;
    const float cc[4] = {c4.x, c4.y, c4.z, c4.w};
    const float ss[4] = {s4.x, s4.y, s4.z, s4.w};
#pragma unroll
    for (int p = 0; p < 4; ++p) {
      float x1 = (float)x[2 * p], x2 = (float)x[2 * p + 1];
      o[2 * p]     = (f16)(x1 * cc[p] - x2 * ss[p]);
      o[2 * p + 1] = (f16)(x2 * cc[p] + x1 * ss[p]);
    }
    *(f16x8*)base = o;
  }
}

// ---- unified attention mega-kernel:
//   blocks [0, nop): oproj for batch b_op (144 out0-blocks + 32 out1-blocks)
//   blocks [nop, nop+npv): PV for batch b_pv reading Psrc
//   blocks [nop+npv, ...): scores for batch b_sc writing f16 Sdst
__global__ __launch_bounds__(256) void k_attn(
    const f16* __restrict__ qb, const f16* __restrict__ kb,
    const f16* __restrict__ mask, f16* __restrict__ Sdst,
    const f16* __restrict__ Psrc, const f16* __restrict__ vt,
    f16* __restrict__ att0, f16* __restrict__ att1,
    const f16* __restrict__ wo0, const f16* __restrict__ wo1,
    float* __restrict__ out0, float* __restrict__ out1,
    int b_sc, int b_pv, int b_op, int npv, int nop)
{
  __shared__ alignas(16) f16 At[128 * 32];
  __shared__ alignas(16) f16 Bt[128 * 32];
  const int idx = blockIdx.x;
  if (idx < nop) {
    // output projection for batch b_op, K=2048
    int by, bx, ldc; const f16 *A, *B; float* C;
    if (idx < 144) { by = b_op * 8 + idx / 18; bx = idx % 18;
                     A = att0 + (size_t)by * 128 * 2048; B = wo0 + (size_t)bx * 128 * 2048;
                     C = out0; ldc = 2304; }
    else           { int j = idx - 144; by = b_op * 4 + (j >> 3); bx = j & 7;
                     A = att1 + (size_t)by * 128 * 2048; B = wo1 + (size_t)bx * 128 * 2048;
                     C = out1; ldc = 1024; }
    const int rowbase = by * 128, colbase = bx * 128;
    gemm_core(At, Bt, A, 2048, B, 2048, 2048, [&](int r, int c, float fv) {
      C[(size_t)(rowbase + r) * ldc + colbase + c] = fv;
    });
  } else if (idx < nop + npv) {
    // PV for batch b_pv, K=1536
    const int j = idx - nop;
    const int h = j / 24, rem = j % 24, by = rem >> 1, bx = rem & 1;
    const f16* A = Psrc + (size_t)h * 1536 * 1536 + (size_t)by * 128 * 1536;
    const f16* B = vt + (size_t)(b_pv * 4 + (h >> 1)) * 256 * 1536 + (size_t)bx * 128 * 1536;
    const int rowbase = by * 128, colbase = bx * 128;
    gemm_core(At, Bt, A, 1536, B, 1536, 1536, [&](int r, int c, float fv) {
      int m = rowbase + r;
      if (m < 1024) att0[((size_t)(b_pv * 1024 + m))       * 2048 + h * 256 + colbase + c] = (f16)fv;
      else          att1[((size_t)(b_pv * 512 + m - 1024)) * 2048 + h * 256 + colbase + c] = (f16)fv;
    });
  } else {
    // scores for batch b_sc, K=256
    const int j = idx - nop - npv;
    const int h = j / 144, rem = j % 144, by = rem / 12, bx = rem % 12;
    const f16* A = qb + (size_t)b_sc * 1536 * 2048 + h * 256 + (size_t)by * 128 * 2048;
    const f16* B = kb + (size_t)b_sc * 1536 * 1024 + (h >> 1) * 256 + (size_t)bx * 128 * 1024;
    f16* Sz = Sdst + (size_t)h * 1536 * 1536;
    const f16* mb = mask + (size_t)b_sc * 1536 * 1536;
    const int rowbase = by * 128, colbase = bx * 128;
    gemm_core(At, Bt, A, 2048, B, 1024, 256, [&](int r, int c, float fv) {
      size_t i = (size_t)(rowbase + r) * 1536 + colbase + c;
      Sz[i] = (f16)(fv * 0.0625f + (float)mb[i]);
    });
  }
}

// ---- wave-per-row softmax over 1536, f16 in/out, in place ------------------
__global__ __launch_bounds__(256) void k_softmax(f16* __restrict__ S)
{
  const int row = blockIdx.x * 4 + (threadIdx.x >> 6);
  const int lane = threadIdx.x & 63;
  f16* p = S + (size_t)row * 1536 + lane * 8;
  f16x8 v0 = *(const f16x8*)p;
  f16x8 v1 = *(const f16x8*)(p + 512);
  f16x8 v2 = *(const f16x8*)(p + 1024);
  float x[24];
#pragma unroll
  for (int i = 0; i < 8; ++i) {
    x[i] = (float)v0[i]; x[8 + i] = (float)v1[i]; x[16 + i] = (float)v2[i];
  }
  float mx = x[0];
#pragma unroll
  for (int i = 1; i < 24; ++i) mx = fmaxf(mx, x[i]);
#pragma unroll
  for (int o = 32; o > 0; o >>= 1) mx = fmaxf(mx, __shfl_xor(mx, o, 64));
  float s = 0.f;
#pragma unroll
  for (int i = 0; i < 24; ++i) { x[i] = __expf(x[i] - mx); s += x[i]; }
#pragma unroll
  for (int o = 32; o > 0; o >>= 1) s += __shfl_xor(s, o, 64);
  const float inv = 1.f / s;
  f16x8 o0, o1, o2;
#pragma unroll
  for (int i = 0; i < 8; ++i) {
    o0[i] = (f16)(x[i] * inv); o1[i] = (f16)(x[8 + i] * inv); o2[i] = (f16)(x[16 + i] * inv);
  }
  *(f16x8*)p = o0; *(f16x8*)(p + 512) = o1; *(f16x8*)(p + 1024) = o2;
}

// ---- flat cast fp32->f16 (pg, ex, Wv0, Wo0, Wv1, Wo1) ----------------------
__global__ __launch_bounds__(256) void k_cast_all(
    const float* __restrict__ s0, const float* __restrict__ s1,
    const float* __restrict__ s2, const float* __restrict__ s3,
    const float* __restrict__ s4, const float* __restrict__ s5,
    f16* __restrict__ ws)
{
  const size_t gid = ((size_t)blockIdx.x * 256 + threadIdx.x) * 4;
  const float* s; size_t off, dst;
  if      (gid < 9437184ull)  { s = s0; off = gid;               dst = 0ull        + off; }
  else if (gid < 11534336ull) { s = s1; off = gid - 9437184ull;  dst = 9437184ull  + off; }
  else if (gid < 13893632ull) { s = s2; off = gid - 11534336ull; dst = 18612224ull + off; }
  else if (gid < 18612224ull) { s = s3; off = gid - 13893632ull; dst = 20971520ull + off; }
  else if (gid < 19660800ull) { s = s4; off = gid - 18612224ull; dst = 28835840ull + off; }
  else                        { s = s5; off = gid - 19660800ull; dst = 29884416ull + off; }
  float4 v = *(const float4*)(s + off);
  f16x4 o = {(f16)v.x, (f16)v.y, (f16)v.z, (f16)v.w};
  *(f16x4*)(ws + dst) = o;
}

// ---- Wq/Wk cast with per-head RoPE pair interleave: dst row h*256+w reads
// src row h*256 + (w>>1) + 128*(w&1).  One block per dst row. ---------------
__global__ __launch_bounds__(256) void k_cast_wr(
    const float* __restrict__ wq0, const float* __restrict__ wk0,
    const float* __restrict__ wq1, const float* __restrict__ wk1,
    f16* __restrict__ W0c, f16* __restrict__ W1c)
{
  const int idx = blockIdx.x;
  const float* src; f16* dstm; int K, r, drow;
  if      (idx < 2048) { src = wq0; dstm = W0c; K = 2304; r = idx;        drow = idx; }
  else if (idx < 3072) { src = wk0; dstm = W0c; K = 2304; r = idx - 2048; drow = idx; }
  else if (idx < 5120) { src = wq1; dstm = W1c; K = 1024; r = idx - 3072; drow = idx - 3072; }
  else                 { src = wk1; dstm = W1c; K = 1024; r = idx - 5120; drow = idx - 3072; }
  const int w = r & 255;
  const int srow = (r & ~255) + (w >> 1) + ((w & 1) << 7);
  const float* sp = src + (size_t)srow * K;
  f16* dp = dstm + (size_t)drow * K;
  for (int c = threadIdx.x * 4; c < K; c += 1024) {
    float4 v = *(const float4*)(sp + c);
    f16x4 o = {(f16)v.x, (f16)v.y, (f16)v.z, (f16)v.w};
    *(f16x4*)(dp + c) = o;
  }
}

// ---------------------------------------------------------------------------
extern "C" void kernel_launch(void* const* d_in, const int* in_sizes, int n_in,
                              void* d_out, int out_size, void* d_ws, size_t ws_size,
                              hipStream_t stream)
{
  (void)in_sizes; (void)n_in; (void)out_size; (void)ws_size;
  const float* pg  = (const float*)d_in[0];
  const float* ex  = (const float*)d_in[1];
  const float* cs  = (const float*)d_in[2];
  const float* sn  = (const float*)d_in[3];
  const float* msk = (const float*)d_in[4];

  char* ws = (char*)d_ws;
  f16* xpg  = (f16*)(ws + 0);           // [4096,2304]   (dead after qkv)
  f16* xex  = (f16*)(ws + 18874368);    // [2048,1024]   (dead after qkv)
  f16* W0c  = (f16*)(ws + 23068672);    // [4096,2304] Wq0i;Wk0i;Wv0 (dead after qkv)
  f16* wo0c = (f16*)(ws + 41943040);    // [2304,2048]
  f16* W1c  = (f16*)(ws + 51380224);    // [4096,1024] Wq1i;Wk1i;Wv1 (dead after qkv)
  f16* wo1c = (f16*)(ws + 59768832);    // [1024,2048]
  f16* qb   = (f16*)(ws + 63963136);    // [B*1536, 2048] f16, pair-interleaved
  f16* kb   = (f16*)(ws + 89128960);    // [B*1536, 1024]
  f16* vb   = (f16*)(ws + 101711872);   // [B*1536, 1024] (dead after post)
  f16* vt   = (f16*)(ws + 114294784);   // [B,4,256,1536]
  f16* att0 = (f16*)(ws + 126877696);   // [B*1024, 2048]
  f16* att1 = (f16*)(ws + 143654912);   // [B*512, 2048]
  f16* S0   = (f16*)(ws + 152043520);   // f16 S/P chunk A: 8*1536*1536
  f16* S1   = (f16*)(ws + 189792256);   // f16 S/P chunk B (ends 227,540,992)
  f16* mkh  = W0c;                      // f16 mask overlays dead W0c (18.9MB)
  float* out0 = (float*)d_out;          // [4,1024,2304]
  float* out1 = out0 + 9437184;         // [4,512,1024]

  // 1) casts
  k_cast_all<<<21248, 256, 0, stream>>>(
      pg, ex, (const float*)d_in[7], (const float*)d_in[8],
      (const float*)d_in[11], (const float*)d_in[12], (f16*)ws);
  k_cast_wr<<<6144, 256, 0, stream>>>(
      (const float*)d_in[5], (const float*)d_in[6],
      (const float*)d_in[9], (const float*)d_in[10], W0c, W1c);

  // 2) fused QKV (both streams, 1536 blocks)
  k_qkv<<<1536, 256, 0, stream>>>(xpg, xex, W0c, W1c, qb, kb, vb);

  // 3) merged post pass: vtrans + mask->f16 + in-place RoPE
  k_post<<<24576, 256, 0, stream>>>(qb, kb, cs, sn, msk, mkh, vb, vt);

  // 4) attention pipeline (double-buffered f16 S chunks); oproj(b) rides in
  //    the scores(b+2) launch
  k_attn<<<1152, 256, 0, stream>>>(qb, kb, mkh, S0, S0, vt, att0, att1, wo0c, wo1c, out0, out1, 0, 0, 0, 0, 0);
  k_softmax<<<3072, 256, 0, stream>>>(S0);
  k_attn<<<1344, 256, 0, stream>>>(qb, kb, mkh, S1, S0, vt, att0, att1, wo0c, wo1c, out0, out1, 1, 0, 0, 192, 0);
  k_softmax<<<3072, 256, 0, stream>>>(S1);
  k_attn<<<1520, 256, 0, stream>>>(qb, kb, mkh, S0, S1, vt, att0, att1, wo0c, wo1c, out0, out1, 2, 1, 0, 192, 176);
  k_softmax<<<3072, 256, 0, stream>>>(S0);
  k_attn<<<1520, 256, 0, stream>>>(qb, kb, mkh, S1, S0, vt, att0, att1, wo0c, wo1c, out0, out1, 3, 2, 1, 192, 176);
  k_softmax<<<3072, 256, 0, stream>>>(S1);

  // 5) tail: PV b3 + oproj b2 (368), then oproj b3 (176)
  k_attn<<<368, 256, 0, stream>>>(qb, kb, mkh, S0, S1, vt, att0, att1, wo0c, wo1c, out0, out1, 0, 3, 2, 192, 176);
  k_attn<<<176, 256, 0, stream>>>(qb, kb, mkh, S0, S1, vt, att0, att1, wo0c, wo1c, out0, out1, 0, 0, 3, 0, 176);
}